// Round 5
// baseline (432.219 us; speedup 1.0000x reference)
//
#include <hip/hip_runtime.h>
#include <math.h>

// Problem constants (reference: N, L, LQ, D, AF, K = 4096, 512, 32, 30, 10, 4)
#define NS 4096
#define LL 512
#define LQS 32
#define DD 30
#define AFN 10
#define KW 4
#define QTR 4                 // quarter-sentence blocks per sentence
#define NBLKA (NS * QTR)      // 16384 streaming blocks
#define QFLT (LL * DD / QTR)  // 3840 floats per quarter

// Workspace layout (floats). All 30x30 tables stored TRANSPOSED: tbl[ii*30+o]
// so the tail's per-lane (lane=o) reads at inner index ii are conflict-free.
enum {
  QRAW = 0,     // [30] mean of question_embeds over LQ
  Q1G  = 30,    // [30] gpool of conv1(q)
  Q2G  = 60,    // [30] gpool of conv2(windowpool(conv1(q)))
  NRM  = 90,    // [3] norms (+3 pad)
  WS1  = 96,    // [900] sum_k conv1_w   (transposed)
  WS2  = 996,   // [900] sum_k conv2_w   (transposed)
  OA0  = 1896,  // [900] 3*w3+2*w2+w1  (row 0)    (transposed)
  OA1  = 2796,  // [900] 2*w3+w2       (row 1)    (transposed)
  OA2  = 3696,  // [900] w3            (row 2)    (transposed)
  OB0  = 4596,  // [900] w0            (row L-3)  (transposed)
  OB1  = 5496,  // [900] w1+2*w0       (row L-2)  (transposed)
  OB2  = 6396,  // [900] w2+2*w1+3*w0  (row L-1)  (transposed)
  WTOT = 7296,
  LOSS = 7296,              // [NS]   per-sentence chosen log-prob (16B aligned)
  PBUF = LOSS + NS,         // [NBLKA*30] per-quarter channel sums
  BNDB = PBUF + NBLKA * DD  // [NS*180]  boundary rows 0,1,2,509,510,511
};                          // total ~4.96 MB of workspace

// ---------------------------------------------------------------------------
// Kernel 1: question pipeline + weight transforms. ONE block. Unchanged from
// the verified 425us version.
// ---------------------------------------------------------------------------
__global__ __launch_bounds__(256) void prep_kernel(
    const float* __restrict__ qe,   // [LQ, D]
    const float* __restrict__ w1,   // [D, D, K]
    const float* __restrict__ b1,   // [D]
    const float* __restrict__ w2,   // [D, D, K]
    const float* __restrict__ b2,   // [D]
    float* __restrict__ ws,
    float* __restrict__ out)
{
    __shared__ float w1s[DD * DD * KW];   // 3600
    __shared__ float w2s[DD * DD * KW];   // 3600
    __shared__ float qT[DD][LQS];
    __shared__ float q1c[DD][LQS + 3];
    __shared__ float q1w[DD][LQS];
    __shared__ float q2c[DD][LQS + 3];
    __shared__ float qpool[3][DD];
    const int tid = threadIdx.x;

    for (int f = tid; f < DD * DD * KW; f += 256) {
        w1s[f] = w1[f];
        w2s[f] = w2[f];
    }
    for (int f = tid; f < LQS * DD; f += 256) {
        qT[f % DD][f / DD] = qe[f];
    }
    __syncthreads();

    for (int idx = tid; idx < DD * (LQS + 3); idx += 256) {
        int o = idx / (LQS + 3), t = idx % (LQS + 3);
        float acc = b1[o];
        for (int i = 0; i < DD; i++) {
            const float* w = w1s + (o * DD + i) * KW;
            #pragma unroll
            for (int k = 0; k < KW; k++) {
                int j = t + k - 3;
                if (j >= 0 && j < LQS) acc += qT[i][j] * w[k];
            }
        }
        q1c[o][t] = acc;
    }
    __syncthreads();

    for (int idx = tid; idx < DD * LQS; idx += 256) {
        int o = idx / LQS, t = idx % LQS;
        q1w[o][t] = 0.25f * (q1c[o][t] + q1c[o][t + 1] + q1c[o][t + 2] + q1c[o][t + 3]);
    }
    __syncthreads();

    for (int idx = tid; idx < DD * (LQS + 3); idx += 256) {
        int o = idx / (LQS + 3), t = idx % (LQS + 3);
        float acc = b2[o];
        for (int i = 0; i < DD; i++) {
            const float* w = w2s + (o * DD + i) * KW;
            #pragma unroll
            for (int k = 0; k < KW; k++) {
                int j = t + k - 3;
                if (j >= 0 && j < LQS) acc += q1w[i][j] * w[k];
            }
        }
        q2c[o][t] = acc;
    }
    __syncthreads();

    if (tid < DD) {
        float a = 0.f;
        for (int t = 0; t < LQS; t++) a += qT[tid][t];
        qpool[0][tid] = a * (1.0f / LQS);
        float g1 = 0.f;
        for (int t = 0; t < LQS + 3; t++) g1 += q1c[tid][t];
        qpool[1][tid] = g1 * (1.0f / (LQS + 3));
        float g2 = 0.f;
        for (int t = 0; t < LQS + 3; t++) g2 += q2c[tid][t];
        qpool[2][tid] = g2 * (1.0f / (LQS + 3));
        ws[QRAW + tid] = qpool[0][tid];
        ws[Q1G + tid]  = qpool[1][tid];
        ws[Q2G + tid]  = qpool[2][tid];
    }
    __syncthreads();
    if (tid < 3) {
        float s = 0.f;
        for (int i = 0; i < DD; i++) { float v = qpool[tid][i]; s += v * v; }
        ws[NRM + tid] = sqrtf(s);
    }
    if (tid >= 3 && tid < 6) ws[NRM + tid] = 0.f;  // pad so ws[0..7296) fully defined
    if (tid == 0) out[0] = 0.0f;

    for (int idx = tid; idx < DD * DD; idx += 256) {
        int o = idx / DD, i = idx % DD;
        int tr = i * DD + o;
        const float* w = w1s + idx * KW;
        float a = w[0], b = w[1], c = w[2], d = w[3];
        ws[WS1 + tr] = a + b + c + d;
        ws[OA0 + tr] = 3.f * d + 2.f * c + b;
        ws[OA1 + tr] = 2.f * d + c;
        ws[OA2 + tr] = d;
        ws[OB0 + tr] = a;
        ws[OB1 + tr] = b + 2.f * a;
        ws[OB2 + tr] = c + 2.f * b + 3.f * a;
        const float* v = w2s + idx * KW;
        ws[WS2 + tr] = v[0] + v[1] + v[2] + v[3];
    }
}

// ---------------------------------------------------------------------------
// Kernel A (v5): PURE streaming. 4 blocks per sentence, each reads a 15 KB
// quarter (240 thr x 4 float4, stride 240), reduces to 30 channel sums via
// the channel trick (3840 % 30 == 0), writes them to pbuf. q0/q3 blocks also
// export the 6 boundary rows (L1-hot). No tables, no tail, 3.8 KB LDS,
// short uniform block lifetime -> max resident blocks, max latency hiding.
// ---------------------------------------------------------------------------
__global__ __launch_bounds__(256) void stream_kernel(
    const float* __restrict__ se,    // [N, L, D]
    float* __restrict__ ws)
{
    const int blk = blockIdx.x;
    const int n = blk >> 2, q = blk & 3;
    const int tid = threadIdx.x;
    const float* base = se + (size_t)n * (LL * DD);
    const float* qb = base + q * QFLT;

    __shared__ float partial[960];

    if (tid < 240) {
        const float4* p = (const float4*)qb + tid;
        float sx = 0.f, sy = 0.f, sz = 0.f, sw = 0.f;
        #pragma unroll
        for (int it = 0; it < 4; it++) {
            float4 v = p[it * 240];
            sx += v.x; sy += v.y; sz += v.z; sw += v.w;
        }
        partial[4 * tid + 0] = sx;
        partial[4 * tid + 1] = sy;
        partial[4 * tid + 2] = sz;
        partial[4 * tid + 3] = sw;
    }
    // boundary rows: q0 owns rows 0..2, q3 owns rows 509..511 (just streamed)
    if (q == 0 && tid < 90) {
        int r = tid / DD, c = tid % DD;
        ws[BNDB + n * 180 + r * DD + c] = base[r * DD + c];
    }
    if (q == 3 && tid < 90) {
        int r = tid / DD, c = tid % DD;
        ws[BNDB + n * 180 + (3 + r) * DD + c] = base[(LL - 3 + r) * DD + c];
    }
    __syncthreads();

    if (tid < DD) {
        float S = 0.f;
        #pragma unroll
        for (int m = 0; m < 32; m++) S += partial[tid + DD * m];
        ws[PBUF + blk * DD + tid] = S;
    }
}

// ---------------------------------------------------------------------------
// Kernel B (v5): tails only. 1024 blocks x 4 waves, one sentence per wave.
// Tables staged once per block (shared by 4 waves). Tail math is byte-for-
// byte the verified v1/v4 algebra; inputs come from pbuf/bndb instead of LDS.
// ---------------------------------------------------------------------------
__global__ __launch_bounds__(256) void post_kernel(
    const float* __restrict__ gaf,   // [N, AF]
    const int*   __restrict__ labels,// [N]
    const float* __restrict__ b1,    // [D]
    const float* __restrict__ b2,    // [D]
    const float* __restrict__ linw,  // [2, 13]
    const float* __restrict__ linb,  // [2]
    const float* __restrict__ ws,
    float* __restrict__ lossbuf,     // [NS]
    float* __restrict__ out)         // [1 + N]
{
    const int tid = threadIdx.x;
    __shared__ float tabs[WTOT];     // 29184 B

    {
        const float4* src = (const float4*)ws;
        float4* dst = (float4*)tabs;
        for (int f = tid; f < WTOT / 4; f += 256) dst[f] = src[f];
    }
    __syncthreads();

    const int w    = tid >> 6;
    const int lane = tid & 63;
    const int n    = blockIdx.x * 4 + w;
    const bool act = (lane < DD);
    const int  ic  = act ? lane : 0;

    // channel sum = sum of the 4 quarter partials
    const float* pb = ws + PBUF + (size_t)(n * 4) * DD;
    float S_i = pb[ic] + pb[DD + ic] + pb[2 * DD + ic] + pb[3 * DD + ic];

    const float* bb = ws + BNDB + (size_t)n * 180;
    float e0r = bb[0 * DD + ic], e1r = bb[1 * DD + ic], e2r = bb[2 * DD + ic];
    float e3r = bb[3 * DD + ic], e4r = bb[4 * DD + ic], e5r = bb[5 * DD + ic];
    float bb1 = b1[ic], bb2 = b2[ic];

    // dotS[o] = sum_ii S[ii]*WS1[ii][o]; edge analogous (tables transposed)
    float dotS = 0.f, edge = 0.f;
    #pragma unroll 6
    for (int ii = 0; ii < DD; ii++) {
        float s   = __shfl(S_i, ii, 64);
        float b0  = __shfl(e0r, ii, 64);
        float b1v = __shfl(e1r, ii, 64);
        float b2v = __shfl(e2r, ii, 64);
        float b3v = __shfl(e3r, ii, 64);
        float b4v = __shfl(e4r, ii, 64);
        float b5v = __shfl(e5r, ii, 64);
        const int t = ii * DD + ic;
        dotS += s * tabs[WS1 + t];
        edge += b0 * tabs[OA0 + t] + b1v * tabs[OA1 + t] + b2v * tabs[OA2 + t]
              + b3v * tabs[OB0 + t] + b4v * tabs[OB1 + t] + b5v * tabs[OB2 + t];
    }
    float s1g = dotS * (1.0f / (LL + 3)) + bb1;
    float Tv  = dotS + (float)LL * bb1 - 0.25f * edge;

    float dot2 = 0.f;
    #pragma unroll 6
    for (int ii = 0; ii < DD; ii++) {
        float tv = __shfl(Tv, ii, 64);
        dot2 += tv * tabs[WS2 + ii * DD + ic];
    }
    float s2g = dot2 * (1.0f / (LL + 3)) + bb2;

    // six length-30 dot products (cos is scale-invariant in s_raw -> use S)
    float qv = (n == 0) ? tabs[QRAW + ic] : tabs[Q2G + ic];
    float q1 = tabs[Q1G + ic];
    float q2 = tabs[Q2G + ic];
    float p0 = act ? qv * S_i : 0.f;
    float p1 = act ? S_i * S_i : 0.f;
    float p2 = act ? q1 * s1g : 0.f;
    float p3 = act ? s1g * s1g : 0.f;
    float p4 = act ? q2 * s2g : 0.f;
    float p5 = act ? s2g * s2g : 0.f;
    #pragma unroll
    for (int off = 32; off >= 1; off >>= 1) {
        p0 += __shfl_xor(p0, off, 64);
        p1 += __shfl_xor(p1, off, 64);
        p2 += __shfl_xor(p2, off, 64);
        p3 += __shfl_xor(p3, off, 64);
        p4 += __shfl_xor(p4, off, 64);
        p5 += __shfl_xor(p5, off, 64);
    }

    if (lane == 0) {
        float nq = (n == 0) ? tabs[NRM + 0] : tabs[NRM + 2];
        float sim1 = p0 / (nq * sqrtf(p1));
        float sim2 = p2 / (tabs[NRM + 1] * sqrtf(p3));
        float sim3 = p4 / (tabs[NRM + 2] * sqrtf(p5));

        float in[3 + AFN];
        in[0] = sim1; in[1] = sim2; in[2] = sim3;
        const float* g = gaf + (size_t)n * AFN;
        #pragma unroll
        for (int j = 0; j < AFN; j++) in[3 + j] = g[j];

        float l0 = linb[0], l1 = linb[1];
        #pragma unroll
        for (int j = 0; j < 3 + AFN; j++) {
            l0 += in[j] * linw[j];
            l1 += in[j] * linw[(3 + AFN) + j];
        }
        float m = fmaxf(l0, l1);
        float lse = m + logf(expf(l0 - m) + expf(l1 - m));
        float lp0 = l0 - lse, lp1 = l1 - lse;
        float mm = fmaxf(lp0, lp1);
        float ee0 = expf(lp0 - mm), ee1 = expf(lp1 - mm);
        out[1 + n] = ee1 / (ee0 + ee1);
        int lab = labels[n];
        lossbuf[n] = (lab == 0) ? lp0 : lp1;   // plain store, no atomic
    }
}

// ---------------------------------------------------------------------------
// Kernel 4: sum the 4096 per-sentence log-probs -> out[0]. One block, ~3us.
// ---------------------------------------------------------------------------
__global__ __launch_bounds__(256) void loss_reduce_kernel(
    const float* __restrict__ lossbuf,  // [NS]
    float* __restrict__ out)
{
    __shared__ float wsum[4];
    const int tid = threadIdx.x;
    const float4* p = (const float4*)lossbuf;   // 1024 float4
    float s = 0.f;
    #pragma unroll
    for (int it = 0; it < 4; it++) {
        float4 v = p[tid + it * 256];
        s += v.x + v.y + v.z + v.w;
    }
    #pragma unroll
    for (int off = 32; off >= 1; off >>= 1) s += __shfl_xor(s, off, 64);
    if ((tid & 63) == 0) wsum[tid >> 6] = s;
    __syncthreads();
    if (tid == 0) out[0] = -(wsum[0] + wsum[1] + wsum[2] + wsum[3]) * (1.0f / NS);
}

// ---------------------------------------------------------------------------
extern "C" void kernel_launch(void* const* d_in, const int* in_sizes, int n_in,
                              void* d_out, int out_size, void* d_ws, size_t ws_size,
                              hipStream_t stream)
{
    (void)in_sizes; (void)n_in; (void)out_size; (void)ws_size;
    const float* se  = (const float*)d_in[0];
    const float* qe  = (const float*)d_in[1];
    const float* gaf = (const float*)d_in[2];
    const int*   lab = (const int*)d_in[3];
    const float* w1  = (const float*)d_in[4];
    const float* b1  = (const float*)d_in[5];
    const float* w2  = (const float*)d_in[6];
    const float* b2  = (const float*)d_in[7];
    const float* lw  = (const float*)d_in[8];
    const float* lb  = (const float*)d_in[9];
    float* out = (float*)d_out;
    float* ws  = (float*)d_ws;   // needs (BNDB + NS*180)*4 ~ 5.0 MB

    hipLaunchKernelGGL(prep_kernel, dim3(1), dim3(256), 0, stream,
                       qe, w1, b1, w2, b2, ws, out);
    hipLaunchKernelGGL(stream_kernel, dim3(NBLKA), dim3(256), 0, stream,
                       se, ws);
    hipLaunchKernelGGL(post_kernel, dim3(NS / 4), dim3(256), 0, stream,
                       gaf, lab, b1, b2, lw, lb, ws, ws + LOSS, out);
    hipLaunchKernelGGL(loss_reduce_kernel, dim3(1), dim3(256), 0, stream,
                       ws + LOSS, out);
}

// Round 7
// 400.563 us; speedup vs baseline: 1.0790x; 1.0790x over previous
//
#include <hip/hip_runtime.h>
#include <math.h>

// Problem constants (reference: N, L, LQ, D, AF, K = 4096, 512, 32, 30, 10, 4)
#define NS 4096
#define LL 512
#define LQS 32
#define DD 30
#define AFN 10
#define KW 4

typedef float v4f __attribute__((ext_vector_type(4)));

// Workspace layout (floats). All 30x30 tables stored TRANSPOSED: tbl[ii*30+o]
// so the tail's per-lane (lane=o) reads at inner index ii are conflict-free.
enum {
  QRAW = 0,     // [30] mean of question_embeds over LQ
  Q1G  = 30,    // [30] gpool of conv1(q)
  Q2G  = 60,    // [30] gpool of conv2(windowpool(conv1(q)))
  NRM  = 90,    // [3] norms (+3 pad)
  WS1  = 96,    // [900] sum_k conv1_w   (transposed)
  WS2  = 996,   // [900] sum_k conv2_w   (transposed)
  OA0  = 1896,  // [900] 3*w3+2*w2+w1  (row 0)    (transposed)
  OA1  = 2796,  // [900] 2*w3+w2       (row 1)    (transposed)
  OA2  = 3696,  // [900] w3            (row 2)    (transposed)
  OB0  = 4596,  // [900] w0            (row L-3)  (transposed)
  OB1  = 5496,  // [900] w1+2*w0       (row L-2)  (transposed)
  OB2  = 6396,  // [900] w2+2*w1+3*w0  (row L-1)  (transposed)
  WTOT = 7296,  // staged wholesale into LDS by every streaming block
  LOSS = 7296   // [4096] per-sentence chosen log-prob (NO atomics) -- 16B aligned
};

// ---------------------------------------------------------------------------
// Kernel 1: question pipeline + weight transforms. ONE block. Unchanged from
// the verified 425/418us versions.
// ---------------------------------------------------------------------------
__global__ __launch_bounds__(256) void prep_kernel(
    const float* __restrict__ qe,   // [LQ, D]
    const float* __restrict__ w1,   // [D, D, K]
    const float* __restrict__ b1,   // [D]
    const float* __restrict__ w2,   // [D, D, K]
    const float* __restrict__ b2,   // [D]
    float* __restrict__ ws,
    float* __restrict__ out)
{
    __shared__ float w1s[DD * DD * KW];   // 3600
    __shared__ float w2s[DD * DD * KW];   // 3600
    __shared__ float qT[DD][LQS];
    __shared__ float q1c[DD][LQS + 3];
    __shared__ float q1w[DD][LQS];
    __shared__ float q2c[DD][LQS + 3];
    __shared__ float qpool[3][DD];
    const int tid = threadIdx.x;

    // coalesced LDS staging of both weight tensors (independent loads)
    for (int f = tid; f < DD * DD * KW; f += 256) {
        w1s[f] = w1[f];
        w2s[f] = w2[f];
    }
    for (int f = tid; f < LQS * DD; f += 256) {
        qT[f % DD][f / DD] = qe[f];
    }
    __syncthreads();

    // conv1 (all operands now in LDS)
    for (int idx = tid; idx < DD * (LQS + 3); idx += 256) {
        int o = idx / (LQS + 3), t = idx % (LQS + 3);
        float acc = b1[o];
        for (int i = 0; i < DD; i++) {
            const float* w = w1s + (o * DD + i) * KW;
            #pragma unroll
            for (int k = 0; k < KW; k++) {
                int j = t + k - 3;
                if (j >= 0 && j < LQS) acc += qT[i][j] * w[k];
            }
        }
        q1c[o][t] = acc;
    }
    __syncthreads();

    // window pool
    for (int idx = tid; idx < DD * LQS; idx += 256) {
        int o = idx / LQS, t = idx % LQS;
        q1w[o][t] = 0.25f * (q1c[o][t] + q1c[o][t + 1] + q1c[o][t + 2] + q1c[o][t + 3]);
    }
    __syncthreads();

    // conv2
    for (int idx = tid; idx < DD * (LQS + 3); idx += 256) {
        int o = idx / (LQS + 3), t = idx % (LQS + 3);
        float acc = b2[o];
        for (int i = 0; i < DD; i++) {
            const float* w = w2s + (o * DD + i) * KW;
            #pragma unroll
            for (int k = 0; k < KW; k++) {
                int j = t + k - 3;
                if (j >= 0 && j < LQS) acc += q1w[i][j] * w[k];
            }
        }
        q2c[o][t] = acc;
    }
    __syncthreads();

    if (tid < DD) {
        float a = 0.f;
        for (int t = 0; t < LQS; t++) a += qT[tid][t];
        qpool[0][tid] = a * (1.0f / LQS);
        float g1 = 0.f;
        for (int t = 0; t < LQS + 3; t++) g1 += q1c[tid][t];
        qpool[1][tid] = g1 * (1.0f / (LQS + 3));
        float g2 = 0.f;
        for (int t = 0; t < LQS + 3; t++) g2 += q2c[tid][t];
        qpool[2][tid] = g2 * (1.0f / (LQS + 3));
        ws[QRAW + tid] = qpool[0][tid];
        ws[Q1G + tid]  = qpool[1][tid];
        ws[Q2G + tid]  = qpool[2][tid];
    }
    __syncthreads();
    if (tid < 3) {
        float s = 0.f;
        for (int i = 0; i < DD; i++) { float v = qpool[tid][i]; s += v * v; }
        ws[NRM + tid] = sqrtf(s);
    }
    if (tid >= 3 && tid < 6) ws[NRM + tid] = 0.f;  // pad so ws[0..7296) is fully defined
    if (tid == 0) out[0] = 0.0f;

    // weight transforms from LDS (stored transposed: [inner i][out o])
    for (int idx = tid; idx < DD * DD; idx += 256) {
        int o = idx / DD, i = idx % DD;
        int tr = i * DD + o;
        const float* w = w1s + idx * KW;
        float a = w[0], b = w[1], c = w[2], d = w[3];
        ws[WS1 + tr] = a + b + c + d;
        ws[OA0 + tr] = 3.f * d + 2.f * c + b;
        ws[OA1 + tr] = 2.f * d + c;
        ws[OA2 + tr] = d;
        ws[OB0 + tr] = a;
        ws[OB1 + tr] = b + 2.f * a;
        ws[OB2 + tr] = c + 2.f * b + 3.f * a;
        const float* v = w2s + idx * KW;
        ws[WS2 + tr] = v[0] + v[1] + v[2] + v[3];
    }
}

// ---------------------------------------------------------------------------
// Kernel 2 (v6): the measured-best v4 structure (418.8us), with ONE change:
// the 16x float4 sentence stream uses NON-TEMPORAL loads, so single-use
// streaming data doesn't thrash L2/L3 allocations against the harness fill's
// dirty write-back drain (960 MiB poison fill leaves ~288 MB dirty in cache
// that drains during our dispatch window).
// ---------------------------------------------------------------------------
__global__ __launch_bounds__(256) void stream_post_kernel(
    const float* __restrict__ se,    // [N, L, D]
    const float* __restrict__ gaf,   // [N, AF]
    const int*   __restrict__ labels,// [N]
    const float* __restrict__ b1,    // [D]
    const float* __restrict__ b2,    // [D]
    const float* __restrict__ linw,  // [2, 13]
    const float* __restrict__ linb,  // [2]
    const float* __restrict__ ws,
    float* __restrict__ lossbuf,     // [NS] per-sentence log-prob
    float* __restrict__ out)         // [1 + N]
{
    const int n   = blockIdx.x;
    const int tid = threadIdx.x;
    const float* base = se + (size_t)n * (LL * DD);

    __shared__ float tabs[WTOT];     // ws[0..7296): q vectors + 8 tables
    __shared__ float partial[960];
    __shared__ float bnd[6][DD];

    // stage tables, coalesced float4 (1824 vec4 / 256 threads ~ 8 each)
    {
        const float4* src = (const float4*)ws;
        float4* dst = (float4*)tabs;
        #pragma unroll
        for (int f = tid; f < WTOT / 4; f += 256) dst[f] = src[f];
    }
    // stream the sentence (non-temporal: no reuse, don't pollute L2/L3)
    if (tid < 240) {
        const v4f* p = (const v4f*)base + tid;
        float sx = 0.f, sy = 0.f, sz = 0.f, sw = 0.f;
        #pragma unroll
        for (int it = 0; it < 16; it++) {
            v4f v = __builtin_nontemporal_load(p + it * 240);
            sx += v.x; sy += v.y; sz += v.z; sw += v.w;
        }
        partial[4 * tid + 0] = sx;
        partial[4 * tid + 1] = sy;
        partial[4 * tid + 2] = sz;
        partial[4 * tid + 3] = sw;
    }
    // boundary rows 0,1,2,509,510,511
    if (tid < 180) {
        int r = tid / DD, c = tid % DD;
        int j = (r < 3) ? r : (LL - 6 + r);
        bnd[r][c] = base[j * DD + c];
    }
    __syncthreads();

    // ---- tail: wave 0 only ----
    if (tid < 64) {
        const int lane = tid;
        const bool act = (lane < DD);
        const int  ic  = act ? lane : 0;

        // channel sum (flat index f aggregates channel f % 30)
        float S_i = 0.f;
        #pragma unroll
        for (int m = 0; m < 32; m++) S_i += partial[ic + DD * m];

        float e0r = bnd[0][ic], e1r = bnd[1][ic], e2r = bnd[2][ic];
        float e3r = bnd[3][ic], e4r = bnd[4][ic], e5r = bnd[5][ic];
        float bb1 = b1[ic], bb2 = b2[ic];

        // dotS[o] = sum_ii S[ii]*WS1[ii][o]; edge analogous (tables transposed)
        float dotS = 0.f, edge = 0.f;
        #pragma unroll 6
        for (int ii = 0; ii < DD; ii++) {
            float s   = __shfl(S_i, ii, 64);
            float b0  = __shfl(e0r, ii, 64);
            float b1v = __shfl(e1r, ii, 64);
            float b2v = __shfl(e2r, ii, 64);
            float b3v = __shfl(e3r, ii, 64);
            float b4v = __shfl(e4r, ii, 64);
            float b5v = __shfl(e5r, ii, 64);
            const int t = ii * DD + ic;
            dotS += s * tabs[WS1 + t];
            edge += b0 * tabs[OA0 + t] + b1v * tabs[OA1 + t] + b2v * tabs[OA2 + t]
                  + b3v * tabs[OB0 + t] + b4v * tabs[OB1 + t] + b5v * tabs[OB2 + t];
        }
        float s1g = dotS * (1.0f / (LL + 3)) + bb1;
        float Tv  = dotS + (float)LL * bb1 - 0.25f * edge;

        float dot2 = 0.f;
        #pragma unroll 6
        for (int ii = 0; ii < DD; ii++) {
            float tv = __shfl(Tv, ii, 64);
            dot2 += tv * tabs[WS2 + ii * DD + ic];
        }
        float s2g = dot2 * (1.0f / (LL + 3)) + bb2;

        // six length-30 dot products (cos is scale-invariant in s_raw -> use S)
        float qv = (n == 0) ? tabs[QRAW + ic] : tabs[Q2G + ic];
        float q1 = tabs[Q1G + ic];
        float q2 = tabs[Q2G + ic];
        float p0 = act ? qv * S_i : 0.f;
        float p1 = act ? S_i * S_i : 0.f;
        float p2 = act ? q1 * s1g : 0.f;
        float p3 = act ? s1g * s1g : 0.f;
        float p4 = act ? q2 * s2g : 0.f;
        float p5 = act ? s2g * s2g : 0.f;
        #pragma unroll
        for (int off = 32; off >= 1; off >>= 1) {
            p0 += __shfl_xor(p0, off, 64);
            p1 += __shfl_xor(p1, off, 64);
            p2 += __shfl_xor(p2, off, 64);
            p3 += __shfl_xor(p3, off, 64);
            p4 += __shfl_xor(p4, off, 64);
            p5 += __shfl_xor(p5, off, 64);
        }

        if (lane == 0) {
            float nq = (n == 0) ? tabs[NRM + 0] : tabs[NRM + 2];
            float sim1 = p0 / (nq * sqrtf(p1));
            float sim2 = p2 / (tabs[NRM + 1] * sqrtf(p3));
            float sim3 = p4 / (tabs[NRM + 2] * sqrtf(p5));

            float in[3 + AFN];
            in[0] = sim1; in[1] = sim2; in[2] = sim3;
            const float* g = gaf + (size_t)n * AFN;
            #pragma unroll
            for (int j = 0; j < AFN; j++) in[3 + j] = g[j];

            float l0 = linb[0], l1 = linb[1];
            #pragma unroll
            for (int j = 0; j < 3 + AFN; j++) {
                l0 += in[j] * linw[j];
                l1 += in[j] * linw[(3 + AFN) + j];
            }
            float m = fmaxf(l0, l1);
            float lse = m + logf(expf(l0 - m) + expf(l1 - m));
            float lp0 = l0 - lse, lp1 = l1 - lse;
            float mm = fmaxf(lp0, lp1);
            float ee0 = expf(lp0 - mm), ee1 = expf(lp1 - mm);
            out[1 + n] = ee1 / (ee0 + ee1);
            int lab = labels[n];
            lossbuf[n] = (lab == 0) ? lp0 : lp1;   // plain store, no atomic
        }
    }
}

// ---------------------------------------------------------------------------
// Kernel 3: sum the 4096 per-sentence log-probs -> out[0]. One block, ~3us.
// ---------------------------------------------------------------------------
__global__ __launch_bounds__(256) void loss_reduce_kernel(
    const float* __restrict__ lossbuf,  // [NS]
    float* __restrict__ out)
{
    __shared__ float wsum[4];
    const int tid = threadIdx.x;
    const float4* p = (const float4*)lossbuf;   // 1024 float4
    float s = 0.f;
    #pragma unroll
    for (int it = 0; it < 4; it++) {
        float4 v = p[tid + it * 256];
        s += v.x + v.y + v.z + v.w;
    }
    #pragma unroll
    for (int off = 32; off >= 1; off >>= 1) s += __shfl_xor(s, off, 64);
    if ((tid & 63) == 0) wsum[tid >> 6] = s;
    __syncthreads();
    if (tid == 0) out[0] = -(wsum[0] + wsum[1] + wsum[2] + wsum[3]) * (1.0f / NS);
}

// ---------------------------------------------------------------------------
extern "C" void kernel_launch(void* const* d_in, const int* in_sizes, int n_in,
                              void* d_out, int out_size, void* d_ws, size_t ws_size,
                              hipStream_t stream)
{
    (void)in_sizes; (void)n_in; (void)out_size; (void)ws_size;
    const float* se  = (const float*)d_in[0];
    const float* qe  = (const float*)d_in[1];
    const float* gaf = (const float*)d_in[2];
    const int*   lab = (const int*)d_in[3];
    const float* w1  = (const float*)d_in[4];
    const float* b1  = (const float*)d_in[5];
    const float* w2  = (const float*)d_in[6];
    const float* b2  = (const float*)d_in[7];
    const float* lw  = (const float*)d_in[8];
    const float* lb  = (const float*)d_in[9];
    float* out = (float*)d_out;
    float* ws  = (float*)d_ws;   // needs (WTOT + NS)*4 = 45568 bytes

    hipLaunchKernelGGL(prep_kernel, dim3(1), dim3(256), 0, stream,
                       qe, w1, b1, w2, b2, ws, out);
    hipLaunchKernelGGL(stream_post_kernel, dim3(NS), dim3(256), 0, stream,
                       se, gaf, lab, b1, b2, lw, lb, ws, ws + LOSS, out);
    hipLaunchKernelGGL(loss_reduce_kernel, dim3(1), dim3(256), 0, stream,
                       ws + LOSS, out);
}